// Round 1
// baseline (11605.211 us; speedup 1.0000x reference)
//
#include <hip/hip_runtime.h>
#include <hip/hip_bf16.h>

#define NFEAT 256
#define NHID  128
#define NCLASS 40

// ---------------- degree ----------------
__global__ void deg_count(const int* __restrict__ rows, float* __restrict__ deg, int E) {
    int e = blockIdx.x * blockDim.x + threadIdx.x;
    if (e < E) atomicAdd(&deg[rows[e]], 1.0f);
}

__global__ void inv_deg(float* __restrict__ deg, int N) {
    int i = blockIdx.x * blockDim.x + threadIdx.x;
    if (i < N) deg[i] = 1.0f / (deg[i] + 1.0f);
}

// ---------------- weight repack: Wt[k][o], o in [0,256): o<128 self, o>=128 neigh ----------------
__global__ void repack_W1(const float* __restrict__ W1, float* __restrict__ Wt) {
    int k = blockIdx.x;        // 0..255
    int o = threadIdx.x;       // 0..255
    float v = (o < 128) ? W1[o * 512 + k] : W1[(o - 128) * 512 + 256 + k];
    Wt[k * 256 + o] = v;
}

__global__ void repack_W2(const float* __restrict__ W2, float* __restrict__ Wt) {
    int k = blockIdx.x;        // 0..127
    int o = threadIdx.x;       // 0..255
    float v = (o < 128) ? W2[o * 256 + k] : W2[(o - 128) * 256 + 128 + k];
    Wt[k * 256 + o] = v;
}

// ---------------- fp32 tiled GEMM: P[M x 256] = X[M x K] @ Wt[K x 256] ----------------
// BM=64, BN=64, BK=16, 256 threads, 4x4 microtile per thread.
__global__ __launch_bounds__(256) void gemm_tiled(const float* __restrict__ X,
                                                  const float* __restrict__ Wt,
                                                  float* __restrict__ P,
                                                  int M, int K) {
    // sX padded to stride 20 floats: keeps 16B-aligned float4 stores, banks map
    // 80B*row -> 2-way conflict only (free per m136).
    __shared__ float sX[64][20];
    __shared__ float sW[16][64];
    const int t  = threadIdx.x;
    const int tx = t & 15, ty = t >> 4;
    const int m0 = blockIdx.x * 64;
    const int n0 = blockIdx.y * 64;

    const int xrow = t >> 2, xk4 = (t & 3) * 4;
    const int wk   = t >> 4, wn4 = (t & 15) * 4;

    float acc[4][4] = {};

    for (int k0 = 0; k0 < K; k0 += 16) {
        int gm = m0 + xrow;
        float4 xv = make_float4(0.f, 0.f, 0.f, 0.f);
        if (gm < M) xv = *reinterpret_cast<const float4*>(&X[(size_t)gm * K + k0 + xk4]);
        *reinterpret_cast<float4*>(&sX[xrow][xk4]) = xv;

        float4 wv = *reinterpret_cast<const float4*>(&Wt[(size_t)(k0 + wk) * 256 + n0 + wn4]);
        *reinterpret_cast<float4*>(&sW[wk][wn4]) = wv;

        __syncthreads();

        #pragma unroll
        for (int k = 0; k < 16; ++k) {
            float a0 = sX[ty * 4 + 0][k];
            float a1 = sX[ty * 4 + 1][k];
            float a2 = sX[ty * 4 + 2][k];
            float a3 = sX[ty * 4 + 3][k];
            float4 b = *reinterpret_cast<const float4*>(&sW[k][tx * 4]);
            acc[0][0] += a0 * b.x; acc[0][1] += a0 * b.y; acc[0][2] += a0 * b.z; acc[0][3] += a0 * b.w;
            acc[1][0] += a1 * b.x; acc[1][1] += a1 * b.y; acc[1][2] += a1 * b.z; acc[1][3] += a1 * b.w;
            acc[2][0] += a2 * b.x; acc[2][1] += a2 * b.y; acc[2][2] += a2 * b.z; acc[2][3] += a2 * b.w;
            acc[3][0] += a3 * b.x; acc[3][1] += a3 * b.y; acc[3][2] += a3 * b.z; acc[3][3] += a3 * b.w;
        }
        __syncthreads();
    }

    #pragma unroll
    for (int i = 0; i < 4; ++i) {
        int gm = m0 + ty * 4 + i;
        if (gm < M) {
            float4 v = make_float4(acc[i][0], acc[i][1], acc[i][2], acc[i][3]);
            *reinterpret_cast<float4*>(&P[(size_t)gm * 256 + n0 + tx * 4]) = v;
        }
    }
}

// ---------------- edge scatter-add: acc[rows[e], :] += src[cols[e], src_off:src_off+128] ----------------
// 32 threads per edge, float4 per thread.
__global__ void scatter_add4(const float* __restrict__ src, int src_stride, int src_off,
                             const int* __restrict__ rows, const int* __restrict__ cols,
                             float* __restrict__ acc, int E) {
    long long tid = (long long)blockIdx.x * blockDim.x + threadIdx.x;
    int e = (int)(tid >> 5);
    if (e >= E) return;
    int lane = (int)(tid & 31);
    int c = cols[e];
    int r = rows[e];
    const float4 v = *reinterpret_cast<const float4*>(&src[(size_t)c * src_stride + src_off + lane * 4]);
    float* dst = &acc[(size_t)r * 128 + lane * 4];
    atomicAdd(dst + 0, v.x);
    atomicAdd(dst + 1, v.y);
    atomicAdd(dst + 2, v.z);
    atomicAdd(dst + 3, v.w);
}

// ---------------- combine: H = relu(P[:, 0:128] + AGG * invdeg) ----------------
__global__ void combine_relu(const float* __restrict__ P, const float* __restrict__ agg,
                             const float* __restrict__ invdeg, float* __restrict__ H, int N) {
    int i = blockIdx.x * blockDim.x + threadIdx.x;
    int n = i >> 5;
    if (n >= N) return;
    int c4 = (i & 31) * 4;
    float id = invdeg[n];
    float4 s = *reinterpret_cast<const float4*>(&P[(size_t)n * 256 + c4]);
    float4 a = *reinterpret_cast<const float4*>(&agg[(size_t)n * 128 + c4]);
    float4 h;
    h.x = fmaxf(fmaf(a.x, id, s.x), 0.f);
    h.y = fmaxf(fmaf(a.y, id, s.y), 0.f);
    h.z = fmaxf(fmaf(a.z, id, s.z), 0.f);
    h.w = fmaxf(fmaf(a.w, id, s.w), 0.f);
    *reinterpret_cast<float4*>(&H[(size_t)n * 128 + c4]) = h;
}

// ---------------- MLP head + log_softmax: one wave per node ----------------
__global__ __launch_bounds__(256) void mlp_logsoftmax(const float* __restrict__ H,
                                                      const float* __restrict__ Wm,
                                                      const float* __restrict__ bm,
                                                      float* __restrict__ out, int N) {
    __shared__ float sh[4][128];
    const int w    = threadIdx.x >> 6;   // wave 0..3
    const int lane = threadIdx.x & 63;
    const int n    = blockIdx.x * 4 + w;
    if (n < N) {
        float2 v = *reinterpret_cast<const float2*>(&H[(size_t)n * 128 + lane * 2]);
        sh[w][lane * 2 + 0] = v.x;
        sh[w][lane * 2 + 1] = v.y;
    }
    __syncthreads();
    if (n >= N) return;

    float logit = -1e30f;
    if (lane < NCLASS) {
        float acc = bm[lane];
        const float* wrow = &Wm[lane * 128];
        #pragma unroll 8
        for (int k = 0; k < 128; ++k) acc += sh[w][k] * wrow[k];
        logit = acc;
    }
    float m = logit;
    #pragma unroll
    for (int off = 32; off; off >>= 1) m = fmaxf(m, __shfl_xor(m, off));
    float e = (lane < NCLASS) ? __expf(logit - m) : 0.f;
    float s = e;
    #pragma unroll
    for (int off = 32; off; off >>= 1) s += __shfl_xor(s, off);
    if (lane < NCLASS) out[(size_t)n * NCLASS + lane] = logit - m - __logf(s);
}

extern "C" void kernel_launch(void* const* d_in, const int* in_sizes, int n_in,
                              void* d_out, int out_size, void* d_ws, size_t ws_size,
                              hipStream_t stream) {
    const float* x    = (const float*)d_in[0];
    const float* W1   = (const float*)d_in[1];
    const float* W2   = (const float*)d_in[2];
    const float* mlpW = (const float*)d_in[3];
    const float* mlpb = (const float*)d_in[4];
    const int*   rows = (const int*)d_in[5];
    const int*   cols = (const int*)d_in[6];

    const int N = in_sizes[0] / NFEAT;   // 100000
    const int E = in_sizes[5];           // 3200000

    char* ws = (char*)d_ws;
    size_t off = 0;
    auto alloc = [&](size_t bytes) -> void* {
        void* p = ws + off;
        off = (off + bytes + 255) & ~(size_t)255;
        return p;
    };
    float* P   = (float*)alloc((size_t)N * 256 * 4);   // [self | neigh-proj]
    float* H   = (float*)alloc((size_t)N * 128 * 4);   // hidden
    float* AGG = (float*)alloc((size_t)N * 128 * 4);   // scatter accumulator
    float* DEG = (float*)alloc((size_t)N * 4);         // deg -> invdeg
    float* Wt1 = (float*)alloc((size_t)256 * 256 * 4);
    float* Wt2 = (float*)alloc((size_t)128 * 256 * 4);

    // degree (ws is poisoned each call -> must zero)
    hipMemsetAsync(DEG, 0, (size_t)N * 4, stream);
    deg_count<<<(E + 255) / 256, 256, 0, stream>>>(rows, DEG, E);
    inv_deg<<<(N + 255) / 256, 256, 0, stream>>>(DEG, N);

    repack_W1<<<256, 256, 0, stream>>>(W1, Wt1);
    repack_W2<<<128, 256, 0, stream>>>(W2, Wt2);

    dim3 ggrid((N + 63) / 64, 4);
    const long long sth = (long long)E * 32;
    const int sblocks = (int)((sth + 255) / 256);
    const int cblocks = (int)(((long long)N * 32 + 255) / 256);

    // ---- layer 1 ----
    gemm_tiled<<<ggrid, 256, 0, stream>>>(x, Wt1, P, N, 256);
    hipMemsetAsync(AGG, 0, (size_t)N * 128 * 4, stream);
    scatter_add4<<<sblocks, 256, 0, stream>>>(P, 256, 128, rows, cols, AGG, E);
    combine_relu<<<cblocks, 256, 0, stream>>>(P, AGG, DEG, H, N);

    // ---- layer 2 ----
    gemm_tiled<<<ggrid, 256, 0, stream>>>(H, Wt2, P, N, 128);
    hipMemsetAsync(AGG, 0, (size_t)N * 128 * 4, stream);
    scatter_add4<<<sblocks, 256, 0, stream>>>(P, 256, 128, rows, cols, AGG, E);
    combine_relu<<<cblocks, 256, 0, stream>>>(P, AGG, DEG, H, N);

    // ---- head ----
    mlp_logsoftmax<<<(N + 3) / 4, 256, 0, stream>>>(H, mlpW, mlpb, (float*)d_out, N);
}

// Round 2
// 1548.356 us; speedup vs baseline: 7.4952x; 7.4952x over previous
//
#include <hip/hip_runtime.h>
#include <hip/hip_bf16.h>

#define NFEAT 256
#define NHID  128
#define NCLASS 40

// ---------------- degree (int) ----------------
__global__ void deg_count(const int* __restrict__ rows, int* __restrict__ deg, int E) {
    int e = blockIdx.x * blockDim.x + threadIdx.x;
    if (e < E) atomicAdd(&deg[rows[e]], 1);
}

__global__ void inv_deg(const int* __restrict__ deg, float* __restrict__ inv, int N) {
    int i = blockIdx.x * blockDim.x + threadIdx.x;
    if (i < N) inv[i] = 1.0f / ((float)deg[i] + 1.0f);
}

// ---------------- CSR build: block sums -> scan -> final scan -> cursor fill ----------------
__global__ void block_sums(const int* __restrict__ deg, int* __restrict__ bsum, int N) {
    __shared__ int s[1024];
    int i = blockIdx.x * 1024 + threadIdx.x;
    s[threadIdx.x] = (i < N) ? deg[i] : 0;
    __syncthreads();
    for (int off = 512; off; off >>= 1) {
        if (threadIdx.x < off) s[threadIdx.x] += s[threadIdx.x + off];
        __syncthreads();
    }
    if (threadIdx.x == 0) bsum[blockIdx.x] = s[0];
}

__global__ void scan_bsums(int* __restrict__ bsum, int* __restrict__ row_ptr, int nb, int N) {
    if (threadIdx.x == 0 && blockIdx.x == 0) {
        int run = 0;
        for (int i = 0; i < nb; ++i) { int v = bsum[i]; bsum[i] = run; run += v; }
        row_ptr[N] = run;   // == E
    }
}

__global__ void scan_final(const int* __restrict__ deg, const int* __restrict__ bsum,
                           int* __restrict__ row_ptr, int N) {
    __shared__ int s[1024];
    int t = threadIdx.x;
    int i = blockIdx.x * 1024 + t;
    int v = (i < N) ? deg[i] : 0;
    s[t] = v;
    __syncthreads();
    for (int off = 1; off < 1024; off <<= 1) {
        int tmp = (t >= off) ? s[t - off] : 0;
        __syncthreads();
        s[t] += tmp;
        __syncthreads();
    }
    if (i < N) row_ptr[i] = bsum[blockIdx.x] + s[t] - v;   // exclusive
}

__global__ void init_cursor(const int* __restrict__ row_ptr, int* __restrict__ cursor, int N) {
    int i = blockIdx.x * blockDim.x + threadIdx.x;
    if (i < N) cursor[i] = row_ptr[i];
}

__global__ void fill_csr(const int* __restrict__ rows, const int* __restrict__ cols,
                         int* __restrict__ cursor, int* __restrict__ csr_cols, int E) {
    int e = blockIdx.x * blockDim.x + threadIdx.x;
    if (e < E) {
        int pos = atomicAdd(&cursor[rows[e]], 1);
        csr_cols[pos] = cols[e];
    }
}

// ---------------- weight repack: Wt[k][o], o in [0,256): o<128 self, o>=128 neigh ----------------
__global__ void repack_W1(const float* __restrict__ W1, float* __restrict__ Wt) {
    int k = blockIdx.x;        // 0..255
    int o = threadIdx.x;       // 0..255
    float v = (o < 128) ? W1[o * 512 + k] : W1[(o - 128) * 512 + 256 + k];
    Wt[k * 256 + o] = v;
}

__global__ void repack_W2(const float* __restrict__ W2, float* __restrict__ Wt) {
    int k = blockIdx.x;        // 0..127
    int o = threadIdx.x;       // 0..255
    float v = (o < 128) ? W2[o * 256 + k] : W2[(o - 128) * 256 + 128 + k];
    Wt[k * 256 + o] = v;
}

// ---------------- fp32 tiled GEMM: P[M x 256] = X[M x K] @ Wt[K x 256] ----------------
__global__ __launch_bounds__(256) void gemm_tiled(const float* __restrict__ X,
                                                  const float* __restrict__ Wt,
                                                  float* __restrict__ P,
                                                  int M, int K) {
    __shared__ float sX[64][20];
    __shared__ float sW[16][64];
    const int t  = threadIdx.x;
    const int tx = t & 15, ty = t >> 4;
    const int m0 = blockIdx.x * 64;
    const int n0 = blockIdx.y * 64;

    const int xrow = t >> 2, xk4 = (t & 3) * 4;
    const int wk   = t >> 4, wn4 = (t & 15) * 4;

    float acc[4][4] = {};

    for (int k0 = 0; k0 < K; k0 += 16) {
        int gm = m0 + xrow;
        float4 xv = make_float4(0.f, 0.f, 0.f, 0.f);
        if (gm < M) xv = *reinterpret_cast<const float4*>(&X[(size_t)gm * K + k0 + xk4]);
        *reinterpret_cast<float4*>(&sX[xrow][xk4]) = xv;

        float4 wv = *reinterpret_cast<const float4*>(&Wt[(size_t)(k0 + wk) * 256 + n0 + wn4]);
        *reinterpret_cast<float4*>(&sW[wk][wn4]) = wv;

        __syncthreads();

        #pragma unroll
        for (int k = 0; k < 16; ++k) {
            float a0 = sX[ty * 4 + 0][k];
            float a1 = sX[ty * 4 + 1][k];
            float a2 = sX[ty * 4 + 2][k];
            float a3 = sX[ty * 4 + 3][k];
            float4 b = *reinterpret_cast<const float4*>(&sW[k][tx * 4]);
            acc[0][0] += a0 * b.x; acc[0][1] += a0 * b.y; acc[0][2] += a0 * b.z; acc[0][3] += a0 * b.w;
            acc[1][0] += a1 * b.x; acc[1][1] += a1 * b.y; acc[1][2] += a1 * b.z; acc[1][3] += a1 * b.w;
            acc[2][0] += a2 * b.x; acc[2][1] += a2 * b.y; acc[2][2] += a2 * b.z; acc[2][3] += a2 * b.w;
            acc[3][0] += a3 * b.x; acc[3][1] += a3 * b.y; acc[3][2] += a3 * b.z; acc[3][3] += a3 * b.w;
        }
        __syncthreads();
    }

    #pragma unroll
    for (int i = 0; i < 4; ++i) {
        int gm = m0 + ty * 4 + i;
        if (gm < M) {
            float4 v = make_float4(acc[i][0], acc[i][1], acc[i][2], acc[i][3]);
            *reinterpret_cast<float4*>(&P[(size_t)gm * 256 + n0 + tx * 4]) = v;
        }
    }
}

// ---------------- gather-aggregate + combine + relu: one wave per node ----------------
// H[n] = relu(P[n, 0:128] + invdeg[n] * sum_{c in nbrs(n)} P[c, 128:256])
__global__ __launch_bounds__(256) void gather_combine(const float* __restrict__ P,
                                                      const int* __restrict__ row_ptr,
                                                      const int* __restrict__ csr_cols,
                                                      const float* __restrict__ invdeg,
                                                      float* __restrict__ H, int N) {
    int node = (blockIdx.x * blockDim.x + threadIdx.x) >> 6;
    if (node >= N) return;
    int lane = threadIdx.x & 63;
    int beg = row_ptr[node], end = row_ptr[node + 1];

    float2 acc = make_float2(0.f, 0.f);
    int p = beg;
    for (; p + 1 < end; p += 2) {
        int c0 = csr_cols[p];
        int c1 = csr_cols[p + 1];
        float2 v0 = *reinterpret_cast<const float2*>(&P[(size_t)c0 * 256 + 128 + lane * 2]);
        float2 v1 = *reinterpret_cast<const float2*>(&P[(size_t)c1 * 256 + 128 + lane * 2]);
        acc.x += v0.x + v1.x;
        acc.y += v0.y + v1.y;
    }
    if (p < end) {
        int c = csr_cols[p];
        float2 v = *reinterpret_cast<const float2*>(&P[(size_t)c * 256 + 128 + lane * 2]);
        acc.x += v.x;
        acc.y += v.y;
    }

    float id = invdeg[node];
    float2 s = *reinterpret_cast<const float2*>(&P[(size_t)node * 256 + lane * 2]);
    float2 h;
    h.x = fmaxf(fmaf(acc.x, id, s.x), 0.f);
    h.y = fmaxf(fmaf(acc.y, id, s.y), 0.f);
    *reinterpret_cast<float2*>(&H[(size_t)node * 128 + lane * 2]) = h;
}

// ---------------- MLP head + log_softmax: one wave per node ----------------
__global__ __launch_bounds__(256) void mlp_logsoftmax(const float* __restrict__ H,
                                                      const float* __restrict__ Wm,
                                                      const float* __restrict__ bm,
                                                      float* __restrict__ out, int N) {
    __shared__ float sh[4][128];
    const int w    = threadIdx.x >> 6;   // wave 0..3
    const int lane = threadIdx.x & 63;
    const int n    = blockIdx.x * 4 + w;
    if (n < N) {
        float2 v = *reinterpret_cast<const float2*>(&H[(size_t)n * 128 + lane * 2]);
        sh[w][lane * 2 + 0] = v.x;
        sh[w][lane * 2 + 1] = v.y;
    }
    __syncthreads();
    if (n >= N) return;

    float logit = -1e30f;
    if (lane < NCLASS) {
        float acc = bm[lane];
        const float* wrow = &Wm[lane * 128];
        #pragma unroll 8
        for (int k = 0; k < 128; ++k) acc += sh[w][k] * wrow[k];
        logit = acc;
    }
    float m = logit;
    #pragma unroll
    for (int off = 32; off; off >>= 1) m = fmaxf(m, __shfl_xor(m, off));
    float e = (lane < NCLASS) ? __expf(logit - m) : 0.f;
    float s = e;
    #pragma unroll
    for (int off = 32; off; off >>= 1) s += __shfl_xor(s, off);
    if (lane < NCLASS) out[(size_t)n * NCLASS + lane] = logit - m - __logf(s);
}

extern "C" void kernel_launch(void* const* d_in, const int* in_sizes, int n_in,
                              void* d_out, int out_size, void* d_ws, size_t ws_size,
                              hipStream_t stream) {
    const float* x    = (const float*)d_in[0];
    const float* W1   = (const float*)d_in[1];
    const float* W2   = (const float*)d_in[2];
    const float* mlpW = (const float*)d_in[3];
    const float* mlpb = (const float*)d_in[4];
    const int*   rows = (const int*)d_in[5];
    const int*   cols = (const int*)d_in[6];

    const int N = in_sizes[0] / NFEAT;   // 100000
    const int E = in_sizes[5];           // 3200000

    char* ws = (char*)d_ws;
    size_t off = 0;
    auto alloc = [&](size_t bytes) -> void* {
        void* p = ws + off;
        off = (off + bytes + 255) & ~(size_t)255;
        return p;
    };
    float* P       = (float*)alloc((size_t)N * 256 * 4);   // [self | neigh-proj]
    float* H       = (float*)alloc((size_t)N * 128 * 4);   // hidden
    int*   DEG     = (int*)  alloc((size_t)N * 4);
    float* INV     = (float*)alloc((size_t)N * 4);
    int*   ROWP    = (int*)  alloc((size_t)(N + 1) * 4);
    int*   CURSOR  = (int*)  alloc((size_t)N * 4);
    int*   CSRC    = (int*)  alloc((size_t)E * 4);
    int*   BSUM    = (int*)  alloc((size_t)4096 * 4);
    float* Wt1     = (float*)alloc((size_t)256 * 256 * 4);
    float* Wt2     = (float*)alloc((size_t)128 * 256 * 4);

    const int nb = (N + 1023) / 1024;

    // ---- graph preprocessing (ws poisoned each call -> rebuild) ----
    hipMemsetAsync(DEG, 0, (size_t)N * 4, stream);
    deg_count<<<(E + 255) / 256, 256, 0, stream>>>(rows, DEG, E);
    inv_deg<<<(N + 255) / 256, 256, 0, stream>>>(DEG, INV, N);
    block_sums<<<nb, 1024, 0, stream>>>(DEG, BSUM, N);
    scan_bsums<<<1, 64, 0, stream>>>(BSUM, ROWP, nb, N);
    scan_final<<<nb, 1024, 0, stream>>>(DEG, BSUM, ROWP, N);
    init_cursor<<<(N + 255) / 256, 256, 0, stream>>>(ROWP, CURSOR, N);
    fill_csr<<<(E + 255) / 256, 256, 0, stream>>>(rows, cols, CURSOR, CSRC, E);

    repack_W1<<<256, 256, 0, stream>>>(W1, Wt1);
    repack_W2<<<128, 256, 0, stream>>>(W2, Wt2);

    dim3 ggrid((N + 63) / 64, 4);
    const int gblocks = (int)(((long long)N * 64 + 255) / 256);

    // ---- layer 1 ----
    gemm_tiled<<<ggrid, 256, 0, stream>>>(x, Wt1, P, N, 256);
    gather_combine<<<gblocks, 256, 0, stream>>>(P, ROWP, CSRC, INV, H, N);

    // ---- layer 2 ----
    gemm_tiled<<<ggrid, 256, 0, stream>>>(H, Wt2, P, N, 128);
    gather_combine<<<gblocks, 256, 0, stream>>>(P, ROWP, CSRC, INV, H, N);

    // ---- head ----
    mlp_logsoftmax<<<(N + 3) / 4, 256, 0, stream>>>(H, mlpW, mlpb, (float*)d_out, N);
}

// Round 3
// 1250.020 us; speedup vs baseline: 9.2840x; 1.2387x over previous
//
#include <hip/hip_runtime.h>
#include <hip/hip_bf16.h>

#define NFEAT 256
#define NHID  128
#define NCLASS 40

typedef __attribute__((ext_vector_type(8))) short short8;
typedef __attribute__((ext_vector_type(4))) float float4v;

__device__ __forceinline__ unsigned short f2bf(float f) {
    union { float f; unsigned u; } v; v.f = f;
    unsigned r = v.u + 0x7fff + ((v.u >> 16) & 1);   // RNE
    return (unsigned short)(r >> 16);
}
__device__ __forceinline__ float bflo(unsigned u) { return __uint_as_float(u << 16); }
__device__ __forceinline__ float bfhi(unsigned u) { return __uint_as_float(u & 0xffff0000u); }

// ---------------- degree (int) ----------------
__global__ void deg_count(const int* __restrict__ rows, int* __restrict__ deg, int E) {
    int e = blockIdx.x * blockDim.x + threadIdx.x;
    if (e < E) atomicAdd(&deg[rows[e]], 1);
}

__global__ void inv_deg(const int* __restrict__ deg, float* __restrict__ inv, int N) {
    int i = blockIdx.x * blockDim.x + threadIdx.x;
    if (i < N) inv[i] = 1.0f / ((float)deg[i] + 1.0f);
}

// ---------------- CSR build ----------------
__global__ void block_sums(const int* __restrict__ deg, int* __restrict__ bsum, int N) {
    __shared__ int s[1024];
    int i = blockIdx.x * 1024 + threadIdx.x;
    s[threadIdx.x] = (i < N) ? deg[i] : 0;
    __syncthreads();
    for (int off = 512; off; off >>= 1) {
        if (threadIdx.x < off) s[threadIdx.x] += s[threadIdx.x + off];
        __syncthreads();
    }
    if (threadIdx.x == 0) bsum[blockIdx.x] = s[0];
}

__global__ void scan_bsums(int* __restrict__ bsum, int* __restrict__ row_ptr, int nb, int N) {
    if (threadIdx.x == 0 && blockIdx.x == 0) {
        int run = 0;
        for (int i = 0; i < nb; ++i) { int v = bsum[i]; bsum[i] = run; run += v; }
        row_ptr[N] = run;
    }
}

__global__ void scan_final(const int* __restrict__ deg, const int* __restrict__ bsum,
                           int* __restrict__ row_ptr, int N) {
    __shared__ int s[1024];
    int t = threadIdx.x;
    int i = blockIdx.x * 1024 + t;
    int v = (i < N) ? deg[i] : 0;
    s[t] = v;
    __syncthreads();
    for (int off = 1; off < 1024; off <<= 1) {
        int tmp = (t >= off) ? s[t - off] : 0;
        __syncthreads();
        s[t] += tmp;
        __syncthreads();
    }
    if (i < N) row_ptr[i] = bsum[blockIdx.x] + s[t] - v;
}

__global__ void init_cursor(const int* __restrict__ row_ptr, int* __restrict__ cursor, int N) {
    int i = blockIdx.x * blockDim.x + threadIdx.x;
    if (i < N) cursor[i] = row_ptr[i];
}

__global__ void fill_csr(const int* __restrict__ rows, const int* __restrict__ cols,
                         int* __restrict__ cursor, int* __restrict__ csr_cols, int E) {
    int e = blockIdx.x * blockDim.x + threadIdx.x;
    if (e < E) {
        int pos = atomicAdd(&cursor[rows[e]], 1);
        csr_cols[pos] = cols[e];
    }
}

// ---------------- fp32 -> bf16 conversion of x ----------------
__global__ void conv_bf16(const float* __restrict__ in, unsigned short* __restrict__ out, long long n4) {
    long long i = (long long)blockIdx.x * blockDim.x + threadIdx.x;
    if (i >= n4) return;
    float4 v = *reinterpret_cast<const float4*>(&in[i * 4]);
    ushort4 o;
    o.x = f2bf(v.x); o.y = f2bf(v.y); o.z = f2bf(v.z); o.w = f2bf(v.w);
    *reinterpret_cast<ushort4*>(&out[i * 4]) = o;
}

// ---------------- weight repack to bf16 K-panel layout: Wp[k0/32][o(256)][k(32)] ----------------
// o<128 -> self block of W, o>=128 -> neigh block.
__global__ void repack_W1p(const float* __restrict__ W1, unsigned short* __restrict__ Wp) {
    int o = blockIdx.x;       // 0..255
    int k = threadIdx.x;      // 0..255
    float v = (o < 128) ? W1[o * 512 + k] : W1[(o - 128) * 512 + 256 + k];
    Wp[(size_t)(k >> 5) * 256 * 32 + o * 32 + (k & 31)] = f2bf(v);
}

__global__ void repack_W2p(const float* __restrict__ W2, unsigned short* __restrict__ Wp) {
    int o = blockIdx.x;       // 0..255
    int k = threadIdx.x;      // 0..127
    float v = (o < 128) ? W2[o * 256 + k] : W2[(o - 128) * 256 + 128 + k];
    Wp[(size_t)(k >> 5) * 256 * 32 + o * 32 + (k & 31)] = f2bf(v);
}

// ---------------- bf16 MFMA GEMM: P[M x 256] = Xb[M x K] @ W (packed) ----------------
// BM=BN=128, BK=32. 256 threads = 4 waves; wave quadrant 64x64 = 4x4 MFMA tiles.
#define LDK 40
__global__ __launch_bounds__(256) void gemm_mfma(const unsigned short* __restrict__ Xb,
                                                 const unsigned short* __restrict__ Wp,
                                                 unsigned short* __restrict__ P,
                                                 int M, int K) {
    __shared__ unsigned short sA[128][LDK];
    __shared__ unsigned short sB[128][LDK];
    const int t    = threadIdx.x;
    const int lane = t & 63;
    const int wave = t >> 6;
    const int m0 = blockIdx.x * 128;
    const int n0 = blockIdx.y * 128;
    const int wm = (wave >> 1) * 64;
    const int wn = (wave & 1) * 64;

    const int lrow = t >> 2;          // 0..63
    const int lk   = (t & 3) * 8;     // 0,8,16,24
    const int r15  = lane & 15;
    const int k8   = (lane >> 4) * 8;

    float4v acc[4][4] = {{{0.f,0.f,0.f,0.f}}};

    for (int k0 = 0; k0 < K; k0 += 32) {
        // stage A: rows lrow and lrow+64
        #pragma unroll
        for (int it = 0; it < 2; ++it) {
            int r  = lrow + it * 64;
            int gm = m0 + r;
            float4 v = make_float4(0.f, 0.f, 0.f, 0.f);
            if (gm < M) v = *reinterpret_cast<const float4*>(&Xb[(size_t)gm * K + k0 + lk]);
            *reinterpret_cast<float4*>(&sA[r][lk]) = v;
        }
        // stage B from packed panel: contiguous 8KB chunk
        const unsigned short* pan = Wp + ((size_t)(k0 >> 5) * 256 + n0) * 32;
        #pragma unroll
        for (int it = 0; it < 2; ++it) {
            int r = lrow + it * 64;
            float4 v = *reinterpret_cast<const float4*>(&pan[(size_t)r * 32 + lk]);
            *reinterpret_cast<float4*>(&sB[r][lk]) = v;
        }
        __syncthreads();

        short8 aF[4], bF[4];
        #pragma unroll
        for (int i = 0; i < 4; ++i)
            aF[i] = *reinterpret_cast<const short8*>(&sA[wm + i * 16 + r15][k8]);
        #pragma unroll
        for (int j = 0; j < 4; ++j)
            bF[j] = *reinterpret_cast<const short8*>(&sB[wn + j * 16 + r15][k8]);
        #pragma unroll
        for (int i = 0; i < 4; ++i)
            #pragma unroll
            for (int j = 0; j < 4; ++j)
                acc[i][j] = __builtin_amdgcn_mfma_f32_16x16x32_bf16(aF[i], bF[j], acc[i][j], 0, 0, 0);
        __syncthreads();
    }

    // epilogue: C/D layout col=lane&15, row=(lane>>4)*4+reg
    #pragma unroll
    for (int i = 0; i < 4; ++i) {
        #pragma unroll
        for (int r = 0; r < 4; ++r) {
            int row = m0 + wm + i * 16 + (lane >> 4) * 4 + r;
            if (row < M) {
                #pragma unroll
                for (int j = 0; j < 4; ++j)
                    P[(size_t)row * 256 + n0 + wn + j * 16 + r15] = f2bf(acc[i][j][r]);
            }
        }
    }
}

// ---------------- gather-aggregate + combine + relu (bf16): one wave per node ----------------
__global__ __launch_bounds__(256) void gather_combine(const unsigned short* __restrict__ P,
                                                      const int* __restrict__ row_ptr,
                                                      const int* __restrict__ csr_cols,
                                                      const float* __restrict__ invdeg,
                                                      unsigned short* __restrict__ H, int N) {
    int node = (blockIdx.x * blockDim.x + threadIdx.x) >> 6;
    if (node >= N) return;
    int lane = threadIdx.x & 63;
    int beg = row_ptr[node], end = row_ptr[node + 1];

    float ax = 0.f, ay = 0.f, bx = 0.f, by = 0.f;
    int p = beg;
    for (; p + 1 < end; p += 2) {
        int c0 = csr_cols[p];
        int c1 = csr_cols[p + 1];
        unsigned u0 = *reinterpret_cast<const unsigned*>(&P[(size_t)c0 * 256 + 128 + lane * 2]);
        unsigned u1 = *reinterpret_cast<const unsigned*>(&P[(size_t)c1 * 256 + 128 + lane * 2]);
        ax += bflo(u0); ay += bfhi(u0);
        bx += bflo(u1); by += bfhi(u1);
    }
    if (p < end) {
        int c = csr_cols[p];
        unsigned u = *reinterpret_cast<const unsigned*>(&P[(size_t)c * 256 + 128 + lane * 2]);
        ax += bflo(u); ay += bfhi(u);
    }
    ax += bx; ay += by;

    float id = invdeg[node];
    unsigned us = *reinterpret_cast<const unsigned*>(&P[(size_t)node * 256 + lane * 2]);
    float hx = fmaxf(fmaf(ax, id, bflo(us)), 0.f);
    float hy = fmaxf(fmaf(ay, id, bfhi(us)), 0.f);
    unsigned out = (unsigned)f2bf(hx) | ((unsigned)f2bf(hy) << 16);
    *reinterpret_cast<unsigned*>(&H[(size_t)node * 128 + lane * 2]) = out;
}

// ---------------- MLP head + log_softmax: one wave per node ----------------
__global__ __launch_bounds__(256) void mlp_logsoftmax(const unsigned short* __restrict__ H,
                                                      const float* __restrict__ Wm,
                                                      const float* __restrict__ bm,
                                                      float* __restrict__ out, int N) {
    __shared__ float sh[4][128];
    const int w    = threadIdx.x >> 6;
    const int lane = threadIdx.x & 63;
    const int n    = blockIdx.x * 4 + w;
    if (n < N) {
        unsigned u = *reinterpret_cast<const unsigned*>(&H[(size_t)n * 128 + lane * 2]);
        sh[w][lane * 2 + 0] = bflo(u);
        sh[w][lane * 2 + 1] = bfhi(u);
    }
    __syncthreads();
    if (n >= N) return;

    float logit = -1e30f;
    if (lane < NCLASS) {
        float acc = bm[lane];
        const float* wrow = &Wm[lane * 128];
        #pragma unroll 8
        for (int k = 0; k < 128; ++k) acc += sh[w][k] * wrow[k];
        logit = acc;
    }
    float m = logit;
    #pragma unroll
    for (int off = 32; off; off >>= 1) m = fmaxf(m, __shfl_xor(m, off));
    float e = (lane < NCLASS) ? __expf(logit - m) : 0.f;
    float s = e;
    #pragma unroll
    for (int off = 32; off; off >>= 1) s += __shfl_xor(s, off);
    if (lane < NCLASS) out[(size_t)n * NCLASS + lane] = logit - m - __logf(s);
}

extern "C" void kernel_launch(void* const* d_in, const int* in_sizes, int n_in,
                              void* d_out, int out_size, void* d_ws, size_t ws_size,
                              hipStream_t stream) {
    const float* x    = (const float*)d_in[0];
    const float* W1   = (const float*)d_in[1];
    const float* W2   = (const float*)d_in[2];
    const float* mlpW = (const float*)d_in[3];
    const float* mlpb = (const float*)d_in[4];
    const int*   rows = (const int*)d_in[5];
    const int*   cols = (const int*)d_in[6];

    const int N = in_sizes[0] / NFEAT;   // 100000
    const int E = in_sizes[5];           // 3200000

    char* ws = (char*)d_ws;
    size_t off = 0;
    auto alloc = [&](size_t bytes) -> void* {
        void* p = ws + off;
        off = (off + bytes + 255) & ~(size_t)255;
        return p;
    };
    unsigned short* Xb  = (unsigned short*)alloc((size_t)N * 256 * 2);  // x in bf16
    unsigned short* P   = (unsigned short*)alloc((size_t)N * 256 * 2);  // [self | neigh-proj] bf16
    unsigned short* H   = (unsigned short*)alloc((size_t)N * 128 * 2);  // hidden bf16
    int*   DEG    = (int*)  alloc((size_t)N * 4);
    float* INV    = (float*)alloc((size_t)N * 4);
    int*   ROWP   = (int*)  alloc((size_t)(N + 1) * 4);
    int*   CURSOR = (int*)  alloc((size_t)N * 4);
    int*   CSRC   = (int*)  alloc((size_t)E * 4);
    int*   BSUM   = (int*)  alloc((size_t)4096 * 4);
    unsigned short* Wp1 = (unsigned short*)alloc((size_t)256 * 256 * 2);
    unsigned short* Wp2 = (unsigned short*)alloc((size_t)128 * 256 * 2);

    const int nb = (N + 1023) / 1024;

    // ---- graph preprocessing ----
    hipMemsetAsync(DEG, 0, (size_t)N * 4, stream);
    deg_count<<<(E + 255) / 256, 256, 0, stream>>>(rows, DEG, E);
    inv_deg<<<(N + 255) / 256, 256, 0, stream>>>(DEG, INV, N);
    block_sums<<<nb, 1024, 0, stream>>>(DEG, BSUM, N);
    scan_bsums<<<1, 64, 0, stream>>>(BSUM, ROWP, nb, N);
    scan_final<<<nb, 1024, 0, stream>>>(DEG, BSUM, ROWP, N);
    init_cursor<<<(N + 255) / 256, 256, 0, stream>>>(ROWP, CURSOR, N);
    fill_csr<<<(E + 255) / 256, 256, 0, stream>>>(rows, cols, CURSOR, CSRC, E);

    // ---- dtype prep ----
    long long n4 = (long long)N * 256 / 4;
    conv_bf16<<<(int)((n4 + 255) / 256), 256, 0, stream>>>(x, Xb, n4);
    repack_W1p<<<256, 256, 0, stream>>>(W1, Wp1);
    repack_W2p<<<256, 128, 0, stream>>>(W2, Wp2);

    dim3 ggrid((N + 127) / 128, 2);
    const int gblocks = (int)(((long long)N * 64 + 255) / 256);

    // ---- layer 1 ----
    gemm_mfma<<<ggrid, 256, 0, stream>>>(Xb, Wp1, P, N, 256);
    gather_combine<<<gblocks, 256, 0, stream>>>(P, ROWP, CSRC, INV, H, N);

    // ---- layer 2 ----
    gemm_mfma<<<ggrid, 256, 0, stream>>>(H, Wp2, P, N, 128);
    gather_combine<<<gblocks, 256, 0, stream>>>(P, ROWP, CSRC, INV, H, N);

    // ---- head ----
    mlp_logsoftmax<<<(N + 3) / 4, 256, 0, stream>>>(H, mlpW, mlpb, (float*)d_out, N);
}